// Round 1
// baseline (492.197 us; speedup 1.0000x reference)
//
#include <hip/hip_runtime.h>
#include <hip/hip_bf16.h>
#include <cstdint>
#include <cstddef>

#define NN    50000
#define FIN   128
#define EE    800000
#define HID_  32
#define HEADS_ 8
#define EMB_  64
#define NEG   0.2f

static __device__ __forceinline__ float lrelu(float v){ return v < 0.f ? NEG * v : v; }

// ---------------- fold att vectors into small projection matrices ----------------
// wt1[f][j], j<8 -> src head j ; j>=8 -> dst head j-8.  (128 x 16)
__global__ void k_build_wt1(const float* __restrict__ Wsrc, const float* __restrict__ Wdst,
                            const float* __restrict__ asrc, const float* __restrict__ adst,
                            float* __restrict__ wt1){
    int idx = blockIdx.x * blockDim.x + threadIdx.x;
    if (idx >= FIN * 16) return;
    int f = idx >> 4, j = idx & 15;
    const float* W; const float* a; int h;
    if (j < 8) { W = Wsrc; a = asrc; h = j; } else { W = Wdst; a = adst; h = j - 8; }
    float s = 0.f;
    #pragma unroll
    for (int c = 0; c < HID_; ++c)
        s += W[(size_t)f * (HEADS_ * HID_) + h * HID_ + c] * a[h * HID_ + c];
    wt1[idx] = s;
}

// wt2[f][j], j=0 src, j=1 dst.  (256 x 2)
__global__ void k_build_wt2(const float* __restrict__ Wsrc, const float* __restrict__ Wdst,
                            const float* __restrict__ asrc, const float* __restrict__ adst,
                            float* __restrict__ wt2){
    int idx = blockIdx.x * blockDim.x + threadIdx.x;
    if (idx >= 256 * 2) return;
    int f = idx >> 1, j = idx & 1;
    const float* W = j ? Wdst : Wsrc;
    const float* a = j ? adst : asrc;
    float s = 0.f;
    #pragma unroll
    for (int c = 0; c < EMB_; ++c) s += W[(size_t)f * EMB_ + c] * a[c];
    wt2[idx] = s;
}

// ---------------- CSR build ----------------
__global__ void k_hist(const int* __restrict__ dst, int* __restrict__ deg){
    int e = blockIdx.x * blockDim.x + threadIdx.x;
    if (e < EE) atomicAdd(&deg[dst[e]], 1);
}

__global__ __launch_bounds__(1024) void k_scan(const int* __restrict__ deg, int* __restrict__ row_ptr){
    __shared__ int sums[1024];
    int tid = threadIdx.x;
    const int chunk = (NN + 1023) >> 10;          // 49
    int begin = tid * chunk;
    int end   = begin + chunk; if (end > NN) end = NN; if (begin > NN) begin = NN;
    int s = 0;
    for (int i = begin; i < end; ++i) s += deg[i];
    sums[tid] = s;
    __syncthreads();
    for (int off = 1; off < 1024; off <<= 1){
        int v = (tid >= off) ? sums[tid - off] : 0;
        __syncthreads();
        sums[tid] += v;
        __syncthreads();
    }
    int run = (tid == 0) ? 0 : sums[tid - 1];
    for (int i = begin; i < end; ++i){ row_ptr[i] = run; run += deg[i]; }
    if (tid == 1023) row_ptr[NN] = sums[1023];
}

__global__ void k_scatter(const int* __restrict__ src, const int* __restrict__ dst,
                          const int* __restrict__ row_ptr, int* __restrict__ fill,
                          int* __restrict__ col){
    int e = blockIdx.x * blockDim.x + threadIdx.x;
    if (e < EE){
        int d = dst[e];
        int pos = row_ptr[d] + atomicAdd(&fill[d], 1);
        col[pos] = src[e];
    }
}

// ---------------- f32 tiled GEMM: C[M,N] = A[M,K] @ B[K,N]; N % 64 == 0, K % 16 == 0 --------
__global__ __launch_bounds__(256) void k_gemm(const float* __restrict__ A, const float* __restrict__ B,
                                              float* __restrict__ C, int M, int N, int K){
    __shared__ float As[16][68];   // [k][m], padded
    __shared__ float Bs[16][68];   // [k][n], padded
    const int tid = threadIdx.x;
    const int tx = tid & 15, ty = tid >> 4;
    const int m0 = blockIdx.x * 64, n0 = blockIdx.y * 64;
    const int la_m = tid >> 2, la_k = (tid & 3) << 2;
    const int lb_k = tid >> 4, lb_n = (tid & 15) << 2;
    float acc[4][4] = {};
    for (int k0 = 0; k0 < K; k0 += 16){
        float4 av = make_float4(0.f, 0.f, 0.f, 0.f);
        if (m0 + la_m < M) av = *(const float4*)&A[(size_t)(m0 + la_m) * K + k0 + la_k];
        float4 bv = *(const float4*)&B[(size_t)(k0 + lb_k) * N + n0 + lb_n];
        As[la_k    ][la_m] = av.x;
        As[la_k + 1][la_m] = av.y;
        As[la_k + 2][la_m] = av.z;
        As[la_k + 3][la_m] = av.w;
        *(float4*)&Bs[lb_k][lb_n] = bv;
        __syncthreads();
        #pragma unroll
        for (int kk = 0; kk < 16; ++kk){
            float4 a4 = *(const float4*)&As[kk][ty << 2];
            float4 b4 = *(const float4*)&Bs[kk][tx << 2];
            acc[0][0] = fmaf(a4.x, b4.x, acc[0][0]);
            acc[0][1] = fmaf(a4.x, b4.y, acc[0][1]);
            acc[0][2] = fmaf(a4.x, b4.z, acc[0][2]);
            acc[0][3] = fmaf(a4.x, b4.w, acc[0][3]);
            acc[1][0] = fmaf(a4.y, b4.x, acc[1][0]);
            acc[1][1] = fmaf(a4.y, b4.y, acc[1][1]);
            acc[1][2] = fmaf(a4.y, b4.z, acc[1][2]);
            acc[1][3] = fmaf(a4.y, b4.w, acc[1][3]);
            acc[2][0] = fmaf(a4.z, b4.x, acc[2][0]);
            acc[2][1] = fmaf(a4.z, b4.y, acc[2][1]);
            acc[2][2] = fmaf(a4.z, b4.z, acc[2][2]);
            acc[2][3] = fmaf(a4.z, b4.w, acc[2][3]);
            acc[3][0] = fmaf(a4.w, b4.x, acc[3][0]);
            acc[3][1] = fmaf(a4.w, b4.y, acc[3][1]);
            acc[3][2] = fmaf(a4.w, b4.z, acc[3][2]);
            acc[3][3] = fmaf(a4.w, b4.w, acc[3][3]);
        }
        __syncthreads();
    }
    #pragma unroll
    for (int i = 0; i < 4; ++i){
        int m = m0 + (ty << 2) + i;
        if (m < M){
            float4 o = make_float4(acc[i][0], acc[i][1], acc[i][2], acc[i][3]);
            *(float4*)&C[(size_t)m * N + n0 + (tx << 2)] = o;
        }
    }
}

// ---------------- attention-score GEMM layer 1: a = x @ wt1  -> a_src[N,8], a_dst[N,8] ------
__global__ __launch_bounds__(256) void k_agemm1(const float* __restrict__ x, const float* __restrict__ wt1,
                                                float* __restrict__ a_src, float* __restrict__ a_dst){
    __shared__ float xs[16][128];
    __shared__ float ws[128 * 16];
    const int tid = threadIdx.x;
    const int n0 = blockIdx.x * 16;
    {   // stage wt1 (2048 floats)
        int t8 = tid * 8;
        *(float4*)&ws[t8]     = *(const float4*)&wt1[t8];
        *(float4*)&ws[t8 + 4] = *(const float4*)&wt1[t8 + 4];
    }
    {   // stage 16 rows of x
        int row = tid >> 4, c0 = (tid & 15) * 8;
        int n = n0 + row;
        float4 v0 = make_float4(0,0,0,0), v1 = make_float4(0,0,0,0);
        if (n < NN){
            v0 = *(const float4*)&x[(size_t)n * FIN + c0];
            v1 = *(const float4*)&x[(size_t)n * FIN + c0 + 4];
        }
        *(float4*)&xs[row][c0]     = v0;
        *(float4*)&xs[row][c0 + 4] = v1;
    }
    __syncthreads();
    const int nl = tid >> 4, j = tid & 15;
    float s = 0.f;
    #pragma unroll
    for (int k4 = 0; k4 < 32; ++k4){
        float4 xv = *(const float4*)&xs[nl][k4 * 4];
        s += xv.x * ws[(k4 * 4 + 0) * 16 + j];
        s += xv.y * ws[(k4 * 4 + 1) * 16 + j];
        s += xv.z * ws[(k4 * 4 + 2) * 16 + j];
        s += xv.w * ws[(k4 * 4 + 3) * 16 + j];
    }
    int node = n0 + nl;
    if (node < NN){
        if (j < 8) a_src[(size_t)node * 8 + j]       = s;
        else       a_dst[(size_t)node * 8 + (j - 8)] = s;
    }
}

// ---------------- attention-score GEMM layer 2 (wave per node) ----------------
__global__ __launch_bounds__(256) void k_agemm2(const float* __restrict__ h, const float* __restrict__ wt2,
                                                float* __restrict__ a_src2, float* __restrict__ a_dst2){
    int wid  = (blockIdx.x * blockDim.x + threadIdx.x) >> 6;
    int lane = threadIdx.x & 63;
    if (wid >= NN) return;
    float wsr[4], wdr[4];
    #pragma unroll
    for (int m = 0; m < 4; ++m){
        wsr[m] = wt2[(m * 64 + lane) * 2 + 0];
        wdr[m] = wt2[(m * 64 + lane) * 2 + 1];
    }
    float ss = 0.f, sd = 0.f;
    #pragma unroll
    for (int m = 0; m < 4; ++m){
        float v = h[(size_t)wid * 256 + m * 64 + lane];
        ss += v * wsr[m];
        sd += v * wdr[m];
    }
    for (int off = 32; off > 0; off >>= 1){
        ss += __shfl_xor(ss, off);
        sd += __shfl_xor(sd, off);
    }
    if (lane == 0){ a_src2[wid] = ss; a_dst2[wid] = sd; }
}

// ---------------- layer-1 aggregation: wave per dst node, softmax fused, +bias +ReLU -------
__global__ __launch_bounds__(256) void k_agg1(const float* __restrict__ hsrc, const float* __restrict__ a_src,
                                              const float* __restrict__ a_dst, const int* __restrict__ row_ptr,
                                              const int* __restrict__ col, const float* __restrict__ b1,
                                              float* __restrict__ hout){
    int node = blockIdx.x * 4 + (threadIdx.x >> 6);
    if (node >= NN) return;
    int lane = threadIdx.x & 63;
    int head = lane >> 3;                       // lane's 4 channels (4l..4l+3) share head l>>3
    float ad = a_dst[(size_t)node * 8 + head];
    const float4* h4 = (const float4*)hsrc;
    float4 acc = make_float4(0.f, 0.f, 0.f, 0.f);
    float den = 0.f;
    int b = row_ptr[node], en = row_ptr[node + 1];
    for (int i = b; i < en; ++i){
        int s = col[i];
        float p = __expf(lrelu(a_src[(size_t)s * 8 + head] + ad));
        float4 v = h4[(size_t)s * 64 + lane];
        acc.x += p * v.x; acc.y += p * v.y; acc.z += p * v.z; acc.w += p * v.w;
        den += p;
    }
    float inv = 1.f / (den + 1e-16f);
    float4 bb = ((const float4*)b1)[lane];
    float4 o;
    o.x = fmaxf(acc.x * inv + bb.x, 0.f);
    o.y = fmaxf(acc.y * inv + bb.y, 0.f);
    o.z = fmaxf(acc.z * inv + bb.z, 0.f);
    o.w = fmaxf(acc.w * inv + bb.w, 0.f);
    ((float4*)hout)[(size_t)node * 64 + lane] = o;
}

// ---------------- layer-2 aggregation: wave per dst node, 1 head, 64 ch, +bias ----------
__global__ __launch_bounds__(256) void k_agg2(const float* __restrict__ hsrc2, const float* __restrict__ a_src2,
                                              const float* __restrict__ a_dst2, const int* __restrict__ row_ptr,
                                              const int* __restrict__ col, const float* __restrict__ b2,
                                              float* __restrict__ out){
    int node = blockIdx.x * 4 + (threadIdx.x >> 6);
    if (node >= NN) return;
    int lane = threadIdx.x & 63;
    float ad = a_dst2[node];
    float acc = 0.f, den = 0.f;
    int b = row_ptr[node], en = row_ptr[node + 1];
    for (int i = b; i < en; ++i){
        int s = col[i];
        float p = __expf(lrelu(a_src2[s] + ad));
        acc += p * hsrc2[(size_t)s * 64 + lane];
        den += p;
    }
    out[(size_t)node * 64 + lane] = acc / (den + 1e-16f) + b2[lane];
}

// ---------------- host ----------------
extern "C" void kernel_launch(void* const* d_in, const int* in_sizes, int n_in,
                              void* d_out, int out_size, void* d_ws, size_t ws_size,
                              hipStream_t stream){
    const float* x        = (const float*)d_in[0];
    const int*   ei       = (const int*)  d_in[1];
    const float* Wsrc1    = (const float*)d_in[2];
    const float* Wdst1    = (const float*)d_in[3];
    const float* att_src1 = (const float*)d_in[4];
    const float* att_dst1 = (const float*)d_in[5];
    const float* b1       = (const float*)d_in[6];
    const float* Wsrc2    = (const float*)d_in[7];
    const float* Wdst2    = (const float*)d_in[8];
    const float* att_src2 = (const float*)d_in[9];
    const float* att_dst2 = (const float*)d_in[10];
    const float* b2       = (const float*)d_in[11];
    float* out = (float*)d_out;
    const int* srcp = ei;
    const int* dstp = ei + EE;

    float* fws = (float*)d_ws;
    size_t off = 0;
    float* hbuf   = fws + off; off += (size_t)NN * 256;   // h_src1, later h_src2
    float* h      = fws + off; off += (size_t)NN * 256;   // relu(layer1 out)
    float* a_src1 = fws + off; off += (size_t)NN * 8;
    float* a_dst1 = fws + off; off += (size_t)NN * 8;
    float* a_src2 = fws + off; off += 50048;
    float* a_dst2 = fws + off; off += 50048;
    float* wt1    = fws + off; off += 128 * 16;
    float* wt2    = fws + off; off += 256 * 2;
    int* deg     = (int*)(fws + off);
    int* row_ptr = deg + NN;
    int* fill    = row_ptr + NN + 1;
    int* col     = fill + NN;

    hipMemsetAsync(deg,  0, NN * sizeof(int), stream);
    hipMemsetAsync(fill, 0, NN * sizeof(int), stream);

    k_build_wt1<<<8, 256, 0, stream>>>(Wsrc1, Wdst1, att_src1, att_dst1, wt1);
    k_build_wt2<<<2, 256, 0, stream>>>(Wsrc2, Wdst2, att_src2, att_dst2, wt2);

    k_hist<<<(EE + 255) / 256, 256, 0, stream>>>(dstp, deg);
    k_scan<<<1, 1024, 0, stream>>>(deg, row_ptr);
    k_scatter<<<(EE + 255) / 256, 256, 0, stream>>>(srcp, dstp, row_ptr, fill, col);

    dim3 g1((NN + 63) / 64, 256 / 64);
    k_gemm<<<g1, 256, 0, stream>>>(x, Wsrc1, hbuf, NN, 256, FIN);
    k_agemm1<<<(NN + 15) / 16, 256, 0, stream>>>(x, wt1, a_src1, a_dst1);

    k_agg1<<<(NN + 3) / 4, 256, 0, stream>>>(hbuf, a_src1, a_dst1, row_ptr, col, b1, h);

    dim3 g2((NN + 63) / 64, 1);
    k_gemm<<<g2, 256, 0, stream>>>(h, Wsrc2, hbuf, NN, 64, 256);
    k_agemm2<<<(NN + 3) / 4, 256, 0, stream>>>(h, wt2, a_src2, a_dst2);

    k_agg2<<<(NN + 3) / 4, 256, 0, stream>>>(hbuf, a_src2, a_dst2, row_ptr, col, b2, out);
}

// Round 2
// 400.539 us; speedup vs baseline: 1.2288x; 1.2288x over previous
//
#include <hip/hip_runtime.h>
#include <hip/hip_bf16.h>
#include <cstdint>
#include <cstddef>

#define NN    50000
#define FIN   128
#define EE    800000
#define HID_  32
#define HEADS_ 8
#define EMB_  64
#define NEG   0.2f

typedef short bf16x8 __attribute__((ext_vector_type(8)));
typedef float f32x4  __attribute__((ext_vector_type(4)));

static __device__ __forceinline__ float lrelu(float v){ return v < 0.f ? NEG * v : v; }
static __device__ __forceinline__ ushort f2bf(float f){
    uint u = __float_as_uint(f);
    uint r = (u + 0x7FFFu + ((u >> 16) & 1u)) >> 16;   // RNE
    return (ushort)r;
}
static __device__ __forceinline__ float bf2f(ushort u){
    return __uint_as_float(((uint)u) << 16);
}

// ---------------- fold att vectors into small projection matrices ----------------
// wt1[f][j], j<8 -> src head j ; j>=8 -> dst head j-8.  (128 x 16)
__global__ void k_build_wt1(const float* __restrict__ Wsrc, const float* __restrict__ Wdst,
                            const float* __restrict__ asrc, const float* __restrict__ adst,
                            float* __restrict__ wt1){
    int idx = blockIdx.x * blockDim.x + threadIdx.x;
    if (idx >= FIN * 16) return;
    int f = idx >> 4, j = idx & 15;
    const float* W; const float* a; int h;
    if (j < 8) { W = Wsrc; a = asrc; h = j; } else { W = Wdst; a = adst; h = j - 8; }
    float s = 0.f;
    #pragma unroll
    for (int c = 0; c < HID_; ++c)
        s += W[(size_t)f * (HEADS_ * HID_) + h * HID_ + c] * a[h * HID_ + c];
    wt1[idx] = s;
}

// wt2[f][j], j=0 src, j=1 dst.  (256 x 2)
__global__ void k_build_wt2(const float* __restrict__ Wsrc, const float* __restrict__ Wdst,
                            const float* __restrict__ asrc, const float* __restrict__ adst,
                            float* __restrict__ wt2){
    int idx = blockIdx.x * blockDim.x + threadIdx.x;
    if (idx >= 256 * 2) return;
    int f = idx >> 1, j = idx & 1;
    const float* W = j ? Wdst : Wsrc;
    const float* a = j ? adst : asrc;
    float s = 0.f;
    #pragma unroll
    for (int c = 0; c < EMB_; ++c) s += W[(size_t)f * EMB_ + c] * a[c];
    wt2[idx] = s;
}

// W1 (f32 [128][256]) -> W1T (bf16 [256][128]) for MFMA B staging
__global__ void k_prep_w1t(const float* __restrict__ W, ushort* __restrict__ w1t){
    int idx = blockIdx.x * blockDim.x + threadIdx.x;   // 32768
    if (idx >= 256 * 128) return;
    int n = idx >> 7, k = idx & 127;
    w1t[idx] = f2bf(W[(size_t)k * 256 + n]);
}

// ---------------- CSR build ----------------
__global__ void k_hist(const int* __restrict__ dst, int* __restrict__ deg, int* __restrict__ rank){
    int e = blockIdx.x * blockDim.x + threadIdx.x;
    if (e < EE) rank[e] = atomicAdd(&deg[dst[e]], 1);
}

__global__ __launch_bounds__(1024) void k_scan(const int* __restrict__ deg, int* __restrict__ row_ptr){
    __shared__ int sums[1024];
    int tid = threadIdx.x;
    const int chunk = (NN + 1023) >> 10;          // 49
    int begin = tid * chunk;
    int end   = begin + chunk; if (end > NN) end = NN; if (begin > NN) begin = NN;
    int s = 0;
    for (int i = begin; i < end; ++i) s += deg[i];
    sums[tid] = s;
    __syncthreads();
    for (int off = 1; off < 1024; off <<= 1){
        int v = (tid >= off) ? sums[tid - off] : 0;
        __syncthreads();
        sums[tid] += v;
        __syncthreads();
    }
    int run = (tid == 0) ? 0 : sums[tid - 1];
    for (int i = begin; i < end; ++i){ row_ptr[i] = run; run += deg[i]; }
    if (tid == 1023) row_ptr[NN] = sums[1023];
}

__global__ void k_scatter(const int* __restrict__ src, const int* __restrict__ dst,
                          const int* __restrict__ row_ptr, const int* __restrict__ rank,
                          int* __restrict__ col){
    int e = blockIdx.x * blockDim.x + threadIdx.x;
    if (e < EE){
        int d = dst[e];
        col[row_ptr[d] + rank[e]] = src[e];
    }
}

// ---------------- MFMA bf16 GEMM layer 1: hbuf_bf[N,256] = bf16( x[N,128] @ W1[128,256] ) ----
// BM=64, BN=128, K=128 single-shot staging. 4 waves; wave w owns rows 16w..16w+15.
__global__ __launch_bounds__(256) void k_gemm1_mfma(const float* __restrict__ x,
                                                    const ushort* __restrict__ w1t,  // [256][128] bf16
                                                    ushort* __restrict__ c){         // [NN][256] bf16
    __shared__ ushort As[64][136];   // [m][k] bf16, +8 pad
    __shared__ ushort Bs[128][136];  // [n][k] bf16, +8 pad
    const int tid = threadIdx.x;
    const int m0 = blockIdx.x * 64;
    const int n0 = blockIdx.y * 128;
    // stage A: 64 rows x 128 f32 -> bf16 (2048 float4, 8 per thread)
    #pragma unroll
    for (int i = 0; i < 8; ++i){
        int idx = tid + i * 256;
        int r = idx >> 5, c4 = idx & 31;          // 32 float4 per row
        int m = m0 + r;
        float4 v = make_float4(0.f, 0.f, 0.f, 0.f);
        if (m < NN) v = *(const float4*)&x[(size_t)m * FIN + c4 * 4];
        ushort4 u; u.x = f2bf(v.x); u.y = f2bf(v.y); u.z = f2bf(v.z); u.w = f2bf(v.w);
        *(ushort4*)&As[r][c4 * 4] = u;
    }
    // stage B: 128 rows (n) x 128 bf16 (2048 16B-chunks, 8 per thread)
    #pragma unroll
    for (int i = 0; i < 8; ++i){
        int idx = tid + i * 256;
        int r = idx >> 4, c8 = idx & 15;          // 16 ushort8-chunks per row
        const ushort4* s4 = (const ushort4*)&w1t[(size_t)(n0 + r) * 128 + c8 * 8];
        *(ushort4*)&Bs[r][c8 * 8]     = s4[0];
        *(ushort4*)&Bs[r][c8 * 8 + 4] = s4[1];
    }
    __syncthreads();
    const int lane = tid & 63;
    const int w    = tid >> 6;
    const int mr   = lane & 15;     // A row / B col within fragment
    const int kg   = lane >> 4;     // k-group
    f32x4 acc[8];
    #pragma unroll
    for (int i = 0; i < 8; ++i) acc[i] = (f32x4){0.f, 0.f, 0.f, 0.f};
    #pragma unroll
    for (int ks = 0; ks < 4; ++ks){
        bf16x8 a = *(const bf16x8*)&As[w * 16 + mr][ks * 32 + kg * 8];
        #pragma unroll
        for (int nf = 0; nf < 8; ++nf){
            bf16x8 b = *(const bf16x8*)&Bs[nf * 16 + mr][ks * 32 + kg * 8];
            acc[nf] = __builtin_amdgcn_mfma_f32_16x16x32_bf16(a, b, acc[nf], 0, 0, 0);
        }
    }
    // store: C col = n0+nf*16+(lane&15), row = m0+w*16+(lane>>4)*4+r   [guide-verified C/D map]
    #pragma unroll
    for (int nf = 0; nf < 8; ++nf){
        int colb = n0 + nf * 16 + mr;
        #pragma unroll
        for (int r = 0; r < 4; ++r){
            int row = m0 + w * 16 + kg * 4 + r;
            if (row < NN) c[(size_t)row * 256 + colb] = f2bf(acc[nf][r]);
        }
    }
}

// ---------------- f32 tiled GEMM: C[M,N] = A[M,K] @ B[K,N]; N % 64 == 0, K % 16 == 0 --------
__global__ __launch_bounds__(256) void k_gemm(const float* __restrict__ A, const float* __restrict__ B,
                                              float* __restrict__ C, int M, int N, int K){
    __shared__ float As[16][68];   // [k][m], padded
    __shared__ float Bs[16][68];   // [k][n], padded
    const int tid = threadIdx.x;
    const int tx = tid & 15, ty = tid >> 4;
    const int m0 = blockIdx.x * 64, n0 = blockIdx.y * 64;
    const int la_m = tid >> 2, la_k = (tid & 3) << 2;
    const int lb_k = tid >> 4, lb_n = (tid & 15) << 2;
    float acc[4][4] = {};
    for (int k0 = 0; k0 < K; k0 += 16){
        float4 av = make_float4(0.f, 0.f, 0.f, 0.f);
        if (m0 + la_m < M) av = *(const float4*)&A[(size_t)(m0 + la_m) * K + k0 + la_k];
        float4 bv = *(const float4*)&B[(size_t)(k0 + lb_k) * N + n0 + lb_n];
        As[la_k    ][la_m] = av.x;
        As[la_k + 1][la_m] = av.y;
        As[la_k + 2][la_m] = av.z;
        As[la_k + 3][la_m] = av.w;
        *(float4*)&Bs[lb_k][lb_n] = bv;
        __syncthreads();
        #pragma unroll
        for (int kk = 0; kk < 16; ++kk){
            float4 a4 = *(const float4*)&As[kk][ty << 2];
            float4 b4 = *(const float4*)&Bs[kk][tx << 2];
            acc[0][0] = fmaf(a4.x, b4.x, acc[0][0]);
            acc[0][1] = fmaf(a4.x, b4.y, acc[0][1]);
            acc[0][2] = fmaf(a4.x, b4.z, acc[0][2]);
            acc[0][3] = fmaf(a4.x, b4.w, acc[0][3]);
            acc[1][0] = fmaf(a4.y, b4.x, acc[1][0]);
            acc[1][1] = fmaf(a4.y, b4.y, acc[1][1]);
            acc[1][2] = fmaf(a4.y, b4.z, acc[1][2]);
            acc[1][3] = fmaf(a4.y, b4.w, acc[1][3]);
            acc[2][0] = fmaf(a4.z, b4.x, acc[2][0]);
            acc[2][1] = fmaf(a4.z, b4.y, acc[2][1]);
            acc[2][2] = fmaf(a4.z, b4.z, acc[2][2]);
            acc[2][3] = fmaf(a4.z, b4.w, acc[2][3]);
            acc[3][0] = fmaf(a4.w, b4.x, acc[3][0]);
            acc[3][1] = fmaf(a4.w, b4.y, acc[3][1]);
            acc[3][2] = fmaf(a4.w, b4.z, acc[3][2]);
            acc[3][3] = fmaf(a4.w, b4.w, acc[3][3]);
        }
        __syncthreads();
    }
    #pragma unroll
    for (int i = 0; i < 4; ++i){
        int m = m0 + (ty << 2) + i;
        if (m < M){
            float4 o = make_float4(acc[i][0], acc[i][1], acc[i][2], acc[i][3]);
            *(float4*)&C[(size_t)m * N + n0 + (tx << 2)] = o;
        }
    }
}

// ---------------- attention-score GEMM layer 1: a = x @ wt1  -> a_src[N,8], a_dst[N,8] ------
__global__ __launch_bounds__(256) void k_agemm1(const float* __restrict__ x, const float* __restrict__ wt1,
                                                float* __restrict__ a_src, float* __restrict__ a_dst){
    __shared__ float xs[16][128];
    __shared__ float ws[128 * 16];
    const int tid = threadIdx.x;
    const int n0 = blockIdx.x * 16;
    {   // stage wt1 (2048 floats)
        int t8 = tid * 8;
        *(float4*)&ws[t8]     = *(const float4*)&wt1[t8];
        *(float4*)&ws[t8 + 4] = *(const float4*)&wt1[t8 + 4];
    }
    {   // stage 16 rows of x
        int row = tid >> 4, c0 = (tid & 15) * 8;
        int n = n0 + row;
        float4 v0 = make_float4(0,0,0,0), v1 = make_float4(0,0,0,0);
        if (n < NN){
            v0 = *(const float4*)&x[(size_t)n * FIN + c0];
            v1 = *(const float4*)&x[(size_t)n * FIN + c0 + 4];
        }
        *(float4*)&xs[row][c0]     = v0;
        *(float4*)&xs[row][c0 + 4] = v1;
    }
    __syncthreads();
    const int nl = tid >> 4, j = tid & 15;
    float s = 0.f;
    #pragma unroll
    for (int k4 = 0; k4 < 32; ++k4){
        float4 xv = *(const float4*)&xs[nl][k4 * 4];
        s += xv.x * ws[(k4 * 4 + 0) * 16 + j];
        s += xv.y * ws[(k4 * 4 + 1) * 16 + j];
        s += xv.z * ws[(k4 * 4 + 2) * 16 + j];
        s += xv.w * ws[(k4 * 4 + 3) * 16 + j];
    }
    int node = n0 + nl;
    if (node < NN){
        if (j < 8) a_src[(size_t)node * 8 + j]       = s;
        else       a_dst[(size_t)node * 8 + (j - 8)] = s;
    }
}

// ---------------- attention-score GEMM layer 2 (wave per node) ----------------
__global__ __launch_bounds__(256) void k_agemm2(const float* __restrict__ h, const float* __restrict__ wt2,
                                                float* __restrict__ a_src2, float* __restrict__ a_dst2){
    int wid  = (blockIdx.x * blockDim.x + threadIdx.x) >> 6;
    int lane = threadIdx.x & 63;
    if (wid >= NN) return;
    float wsr[4], wdr[4];
    #pragma unroll
    for (int m = 0; m < 4; ++m){
        wsr[m] = wt2[(m * 64 + lane) * 2 + 0];
        wdr[m] = wt2[(m * 64 + lane) * 2 + 1];
    }
    float ss = 0.f, sd = 0.f;
    #pragma unroll
    for (int m = 0; m < 4; ++m){
        float v = h[(size_t)wid * 256 + m * 64 + lane];
        ss += v * wsr[m];
        sd += v * wdr[m];
    }
    for (int off = 32; off > 0; off >>= 1){
        ss += __shfl_xor(ss, off);
        sd += __shfl_xor(sd, off);
    }
    if (lane == 0){ a_src2[wid] = ss; a_dst2[wid] = sd; }
}

// ---------------- layer-1 aggregation: wave per dst node, softmax fused, +bias +ReLU -------
// hsrc is bf16 [NN][256]
__global__ __launch_bounds__(256) void k_agg1(const ushort* __restrict__ hsrc, const float* __restrict__ a_src,
                                              const float* __restrict__ a_dst, const int* __restrict__ row_ptr,
                                              const int* __restrict__ col, const float* __restrict__ b1,
                                              float* __restrict__ hout){
    int node = blockIdx.x * 4 + (threadIdx.x >> 6);
    if (node >= NN) return;
    int lane = threadIdx.x & 63;
    int head = lane >> 3;                       // lane's 4 channels (4l..4l+3) share head l>>3
    float ad = a_dst[(size_t)node * 8 + head];
    const ushort4* h4 = (const ushort4*)hsrc;
    float4 acc = make_float4(0.f, 0.f, 0.f, 0.f);
    float den = 0.f;
    int b = row_ptr[node], en = row_ptr[node + 1];
    for (int i = b; i < en; ++i){
        int s = col[i];
        float p = __expf(lrelu(a_src[(size_t)s * 8 + head] + ad));
        ushort4 v = h4[(size_t)s * 64 + lane];
        acc.x += p * bf2f(v.x); acc.y += p * bf2f(v.y);
        acc.z += p * bf2f(v.z); acc.w += p * bf2f(v.w);
        den += p;
    }
    float inv = 1.f / (den + 1e-16f);
    float4 bb = ((const float4*)b1)[lane];
    float4 o;
    o.x = fmaxf(acc.x * inv + bb.x, 0.f);
    o.y = fmaxf(acc.y * inv + bb.y, 0.f);
    o.z = fmaxf(acc.z * inv + bb.z, 0.f);
    o.w = fmaxf(acc.w * inv + bb.w, 0.f);
    ((float4*)hout)[(size_t)node * 64 + lane] = o;
}

// ---------------- layer-2 aggregation: wave per dst node, 1 head, 64 ch, +bias ----------
__global__ __launch_bounds__(256) void k_agg2(const float* __restrict__ hsrc2, const float* __restrict__ a_src2,
                                              const float* __restrict__ a_dst2, const int* __restrict__ row_ptr,
                                              const int* __restrict__ col, const float* __restrict__ b2,
                                              float* __restrict__ out){
    int node = blockIdx.x * 4 + (threadIdx.x >> 6);
    if (node >= NN) return;
    int lane = threadIdx.x & 63;
    float ad = a_dst2[node];
    float acc = 0.f, den = 0.f;
    int b = row_ptr[node], en = row_ptr[node + 1];
    for (int i = b; i < en; ++i){
        int s = col[i];
        float p = __expf(lrelu(a_src2[s] + ad));
        acc += p * hsrc2[(size_t)s * 64 + lane];
        den += p;
    }
    out[(size_t)node * 64 + lane] = acc / (den + 1e-16f) + b2[lane];
}

// ---------------- host ----------------
extern "C" void kernel_launch(void* const* d_in, const int* in_sizes, int n_in,
                              void* d_out, int out_size, void* d_ws, size_t ws_size,
                              hipStream_t stream){
    const float* x        = (const float*)d_in[0];
    const int*   ei       = (const int*)  d_in[1];
    const float* Wsrc1    = (const float*)d_in[2];
    const float* Wdst1    = (const float*)d_in[3];
    const float* att_src1 = (const float*)d_in[4];
    const float* att_dst1 = (const float*)d_in[5];
    const float* b1       = (const float*)d_in[6];
    const float* Wsrc2    = (const float*)d_in[7];
    const float* Wdst2    = (const float*)d_in[8];
    const float* att_src2 = (const float*)d_in[9];
    const float* att_dst2 = (const float*)d_in[10];
    const float* b2       = (const float*)d_in[11];
    float* out = (float*)d_out;
    const int* srcp = ei;
    const int* dstp = ei + EE;

    char* base = (char*)d_ws;
    ushort* hbuf_bf = (ushort*)base;  base += (size_t)NN * 256 * 2;   // 25.6 MB bf16 h_src1
    float*  h       = (float*)base;   base += (size_t)NN * 256 * 4;   // 51.2 MB relu(layer1)
    float*  hbuf2   = (float*)base;   base += (size_t)NN * 64 * 4;    // 12.8 MB h_src2 f32
    float*  a_src1  = (float*)base;   base += (size_t)NN * 8 * 4;
    float*  a_dst1  = (float*)base;   base += (size_t)NN * 8 * 4;
    float*  a_src2  = (float*)base;   base += (size_t)NN * 4;
    float*  a_dst2  = (float*)base;   base += (size_t)NN * 4;
    float*  wt1     = (float*)base;   base += 2048 * 4;
    float*  wt2     = (float*)base;   base += 512 * 4;
    ushort* w1t     = (ushort*)base;  base += 32768 * 2;
    int* deg     = (int*)base;        base += (size_t)NN * 4;
    int* row_ptr = (int*)base;        base += (size_t)(NN + 1) * 4;
    int* rank    = (int*)base;        base += (size_t)EE * 4;
    int* col     = (int*)base;        base += (size_t)EE * 4;

    hipMemsetAsync(deg, 0, NN * sizeof(int), stream);

    k_build_wt1<<<8, 256, 0, stream>>>(Wsrc1, Wdst1, att_src1, att_dst1, wt1);
    k_build_wt2<<<2, 256, 0, stream>>>(Wsrc2, Wdst2, att_src2, att_dst2, wt2);
    k_prep_w1t<<<128, 256, 0, stream>>>(Wsrc1, w1t);

    k_hist<<<(EE + 255) / 256, 256, 0, stream>>>(dstp, deg, rank);
    k_scan<<<1, 1024, 0, stream>>>(deg, row_ptr);
    k_scatter<<<(EE + 255) / 256, 256, 0, stream>>>(srcp, dstp, row_ptr, rank, col);

    dim3 g1((NN + 63) / 64, 2);
    k_gemm1_mfma<<<g1, 256, 0, stream>>>(x, w1t, hbuf_bf);
    k_agemm1<<<(NN + 15) / 16, 256, 0, stream>>>(x, wt1, a_src1, a_dst1);

    k_agg1<<<(NN + 3) / 4, 256, 0, stream>>>(hbuf_bf, a_src1, a_dst1, row_ptr, col, b1, h);

    dim3 g2((NN + 63) / 64, 1);
    k_gemm<<<g2, 256, 0, stream>>>(h, Wsrc2, hbuf2, NN, 64, 256);
    k_agemm2<<<(NN + 3) / 4, 256, 0, stream>>>(h, wt2, a_src2, a_dst2);

    k_agg2<<<(NN + 3) / 4, 256, 0, stream>>>(hbuf2, a_src2, a_dst2, row_ptr, col, b2, out);
}

// Round 4
// 282.398 us; speedup vs baseline: 1.7429x; 1.4184x over previous
//
#include <hip/hip_runtime.h>
#include <hip/hip_bf16.h>
#include <cstdint>
#include <cstddef>

#define NN    50000
#define FIN   128
#define EE    800000
#define HID_  32
#define HEADS_ 8
#define EMB_  64
#define NEG   0.2f

typedef short bf16x8 __attribute__((ext_vector_type(8)));
typedef float f32x4  __attribute__((ext_vector_type(4)));

static __device__ __forceinline__ float lrelu(float v){ return v < 0.f ? NEG * v : v; }
static __device__ __forceinline__ ushort f2bf(float f){
    uint u = __float_as_uint(f);
    uint r = (u + 0x7FFFu + ((u >> 16) & 1u)) >> 16;   // RNE
    return (ushort)r;
}
static __device__ __forceinline__ float bf2f(ushort u){
    return __uint_as_float(((uint)u) << 16);
}

// ---------------- fold att vectors into small projection matrices ----------------
// wt1bf[j][f] (16 x 128 bf16): j<8 -> src head j ; j>=8 -> dst head j-8
__global__ void k_build_wt1(const float* __restrict__ Wsrc, const float* __restrict__ Wdst,
                            const float* __restrict__ asrc, const float* __restrict__ adst,
                            ushort* __restrict__ wt1bf){
    int idx = blockIdx.x * blockDim.x + threadIdx.x;
    if (idx >= FIN * 16) return;
    int f = idx >> 4, j = idx & 15;
    const float* W; const float* a; int h;
    if (j < 8) { W = Wsrc; a = asrc; h = j; } else { W = Wdst; a = adst; h = j - 8; }
    float s = 0.f;
    #pragma unroll
    for (int c = 0; c < HID_; ++c)
        s += W[(size_t)f * (HEADS_ * HID_) + h * HID_ + c] * a[h * HID_ + c];
    wt1bf[j * 128 + f] = f2bf(s);
}

// wt2[j*256+f], j=0 src, j=1 dst (f32)
__global__ void k_build_wt2(const float* __restrict__ Wsrc, const float* __restrict__ Wdst,
                            const float* __restrict__ asrc, const float* __restrict__ adst,
                            float* __restrict__ wt2){
    int idx = blockIdx.x * blockDim.x + threadIdx.x;
    if (idx >= 256 * 2) return;
    int f = idx >> 1, j = idx & 1;
    const float* W = j ? Wdst : Wsrc;
    const float* a = j ? adst : asrc;
    float s = 0.f;
    #pragma unroll
    for (int c = 0; c < EMB_; ++c) s += W[(size_t)f * EMB_ + c] * a[c];
    wt2[j * 256 + f] = s;
}

// W1 (f32 [128][256]) -> W1T (bf16 [256][128])
__global__ void k_prep_w1t(const float* __restrict__ W, ushort* __restrict__ w1t){
    int idx = blockIdx.x * blockDim.x + threadIdx.x;   // 32768
    if (idx >= 256 * 128) return;
    int n = idx >> 7, k = idx & 127;
    w1t[idx] = f2bf(W[(size_t)k * 256 + n]);
}

// W2 (f32 [256][64]) -> W2T (bf16 [64][256])
__global__ void k_prep_w2t(const float* __restrict__ W, ushort* __restrict__ w2t){
    int idx = blockIdx.x * blockDim.x + threadIdx.x;   // 16384
    if (idx >= 64 * 256) return;
    int n = idx >> 8, k = idx & 255;
    w2t[idx] = f2bf(W[(size_t)k * 64 + n]);
}

// ---------------- CSR build ----------------
__global__ void k_hist(const int* __restrict__ dst, int* __restrict__ deg, int* __restrict__ rank){
    int e = blockIdx.x * blockDim.x + threadIdx.x;
    if (e < EE) rank[e] = atomicAdd(&deg[dst[e]], 1);
}

__global__ __launch_bounds__(1024) void k_scan(const int* __restrict__ deg, int* __restrict__ row_ptr){
    __shared__ int sums[1024];
    int tid = threadIdx.x;
    const int chunk = (NN + 1023) >> 10;          // 49
    int begin = tid * chunk;
    int end   = begin + chunk; if (end > NN) end = NN; if (begin > NN) begin = NN;
    int s = 0;
    for (int i = begin; i < end; ++i) s += deg[i];
    sums[tid] = s;
    __syncthreads();
    for (int off = 1; off < 1024; off <<= 1){
        int v = (tid >= off) ? sums[tid - off] : 0;
        __syncthreads();
        sums[tid] += v;
        __syncthreads();
    }
    int run = (tid == 0) ? 0 : sums[tid - 1];
    for (int i = begin; i < end; ++i){ row_ptr[i] = run; run += deg[i]; }
    if (tid == 1023) row_ptr[NN] = sums[1023];
}

__global__ void k_scatter(const int* __restrict__ src, const int* __restrict__ dst,
                          const int* __restrict__ row_ptr, const int* __restrict__ rank,
                          int* __restrict__ col){
    int e = blockIdx.x * blockDim.x + threadIdx.x;
    if (e < EE){
        int d = dst[e];
        col[row_ptr[d] + rank[e]] = src[e];
    }
}

// ---------------- MFMA bf16 GEMM layer 1 + fused attention scores ----------------
// hbuf_bf[N,256] = bf16( x[N,128] @ W1[128,256] ); blockIdx.y==0 also emits
// a_src1/a_dst1[N,8] = x @ wt1 via one extra B-fragment.
__global__ __launch_bounds__(256) void k_gemm1_mfma(const float* __restrict__ x,
                                                    const ushort* __restrict__ w1t,   // [256][128] bf16
                                                    const ushort* __restrict__ wt1bf, // [16][128] bf16
                                                    ushort* __restrict__ c,           // [NN][256] bf16
                                                    float* __restrict__ a_src1,
                                                    float* __restrict__ a_dst1){
    __shared__ ushort As[64][136];
    __shared__ ushort Bs[128][136];
    __shared__ ushort Bsa[16][136];
    const int tid = threadIdx.x;
    const int m0 = blockIdx.x * 64;
    const int n0 = blockIdx.y * 128;
    // stage A: 64 rows x 128 f32 -> bf16
    #pragma unroll
    for (int i = 0; i < 8; ++i){
        int idx = tid + i * 256;
        int r = idx >> 5, c4 = idx & 31;
        int m = m0 + r;
        float4 v = make_float4(0.f, 0.f, 0.f, 0.f);
        if (m < NN) v = *(const float4*)&x[(size_t)m * FIN + c4 * 4];
        ushort4 u; u.x = f2bf(v.x); u.y = f2bf(v.y); u.z = f2bf(v.z); u.w = f2bf(v.w);
        *(ushort4*)&As[r][c4 * 4] = u;
    }
    // stage B: 128 n-rows x 128 k bf16
    #pragma unroll
    for (int i = 0; i < 8; ++i){
        int idx = tid + i * 256;
        int r = idx >> 4, c8 = idx & 15;
        const ushort4* s4 = (const ushort4*)&w1t[(size_t)(n0 + r) * 128 + c8 * 8];
        *(ushort4*)&Bs[r][c8 * 8]     = s4[0];
        *(ushort4*)&Bs[r][c8 * 8 + 4] = s4[1];
    }
    // stage Bsa: 16 x 128 bf16 (only needed when y==0) — BOTH ushort4 halves!
    if (blockIdx.y == 0){
        int r = tid >> 4, c8 = tid & 15;
        const ushort4* s4 = (const ushort4*)&wt1bf[r * 128 + c8 * 8];
        *(ushort4*)&Bsa[r][c8 * 8]     = s4[0];
        *(ushort4*)&Bsa[r][c8 * 8 + 4] = s4[1];
    }
    __syncthreads();
    const int lane = tid & 63;
    const int w    = tid >> 6;
    const int mr   = lane & 15;
    const int kg   = lane >> 4;
    f32x4 acc[8];
    #pragma unroll
    for (int i = 0; i < 8; ++i) acc[i] = (f32x4){0.f, 0.f, 0.f, 0.f};
    f32x4 acca = (f32x4){0.f, 0.f, 0.f, 0.f};
    #pragma unroll
    for (int ks = 0; ks < 4; ++ks){
        bf16x8 a = *(const bf16x8*)&As[w * 16 + mr][ks * 32 + kg * 8];
        #pragma unroll
        for (int nf = 0; nf < 8; ++nf){
            bf16x8 b = *(const bf16x8*)&Bs[nf * 16 + mr][ks * 32 + kg * 8];
            acc[nf] = __builtin_amdgcn_mfma_f32_16x16x32_bf16(a, b, acc[nf], 0, 0, 0);
        }
        if (blockIdx.y == 0){
            bf16x8 ba = *(const bf16x8*)&Bsa[mr][ks * 32 + kg * 8];
            acca = __builtin_amdgcn_mfma_f32_16x16x32_bf16(a, ba, acca, 0, 0, 0);
        }
    }
    #pragma unroll
    for (int nf = 0; nf < 8; ++nf){
        int colb = n0 + nf * 16 + mr;
        #pragma unroll
        for (int r = 0; r < 4; ++r){
            int row = m0 + w * 16 + kg * 4 + r;
            if (row < NN) c[(size_t)row * 256 + colb] = f2bf(acc[nf][r]);
        }
    }
    if (blockIdx.y == 0){
        int j = mr;
        #pragma unroll
        for (int r = 0; r < 4; ++r){
            int row = m0 + w * 16 + kg * 4 + r;
            if (row < NN){
                if (j < 8) a_src1[(size_t)row * 8 + j]       = acca[r];
                else       a_dst1[(size_t)row * 8 + (j - 8)] = acca[r];
            }
        }
    }
}

// ---------------- MFMA bf16 GEMM layer 2: h2[N,64] = bf16( h[N,256] @ W2[256,64] ) -------
__global__ __launch_bounds__(256) void k_gemm2_mfma(const ushort* __restrict__ hbf,   // [NN][256]
                                                    const ushort* __restrict__ w2t,   // [64][256]
                                                    ushort* __restrict__ c2){         // [NN][64]
    __shared__ ushort As[64][264];
    __shared__ ushort Bs[64][264];
    const int tid = threadIdx.x;
    const int m0 = blockIdx.x * 64;
    #pragma unroll
    for (int i = 0; i < 8; ++i){
        int idx = tid + i * 256;
        int r = idx >> 5, c8 = idx & 31;
        int m = m0 + r;
        ushort4 v0 = make_ushort4(0,0,0,0), v1 = make_ushort4(0,0,0,0);
        if (m < NN){
            const ushort4* s4 = (const ushort4*)&hbf[(size_t)m * 256 + c8 * 8];
            v0 = s4[0]; v1 = s4[1];
        }
        *(ushort4*)&As[r][c8 * 8]     = v0;
        *(ushort4*)&As[r][c8 * 8 + 4] = v1;
    }
    #pragma unroll
    for (int i = 0; i < 8; ++i){
        int idx = tid + i * 256;
        int r = idx >> 5, c8 = idx & 31;
        const ushort4* s4 = (const ushort4*)&w2t[(size_t)r * 256 + c8 * 8];
        *(ushort4*)&Bs[r][c8 * 8]     = s4[0];
        *(ushort4*)&Bs[r][c8 * 8 + 4] = s4[1];
    }
    __syncthreads();
    const int lane = tid & 63;
    const int w    = tid >> 6;
    const int mr   = lane & 15;
    const int kg   = lane >> 4;
    f32x4 acc[4];
    #pragma unroll
    for (int i = 0; i < 4; ++i) acc[i] = (f32x4){0.f, 0.f, 0.f, 0.f};
    #pragma unroll
    for (int ks = 0; ks < 8; ++ks){
        bf16x8 a = *(const bf16x8*)&As[w * 16 + mr][ks * 32 + kg * 8];
        #pragma unroll
        for (int nf = 0; nf < 4; ++nf){
            bf16x8 b = *(const bf16x8*)&Bs[nf * 16 + mr][ks * 32 + kg * 8];
            acc[nf] = __builtin_amdgcn_mfma_f32_16x16x32_bf16(a, b, acc[nf], 0, 0, 0);
        }
    }
    #pragma unroll
    for (int nf = 0; nf < 4; ++nf){
        int colb = nf * 16 + mr;
        #pragma unroll
        for (int r = 0; r < 4; ++r){
            int row = m0 + w * 16 + kg * 4 + r;
            if (row < NN) c2[(size_t)row * 64 + colb] = f2bf(acc[nf][r]);
        }
    }
}

// ---------------- layer-1 aggregation (wave/node, batch-4 gathers) + fused layer-2 scores -
__global__ __launch_bounds__(256) void k_agg1(const ushort* __restrict__ hsrc, const float* __restrict__ a_src,
                                              const float* __restrict__ a_dst, const int* __restrict__ row_ptr,
                                              const int* __restrict__ col, const float* __restrict__ b1,
                                              const float* __restrict__ wt2,
                                              ushort* __restrict__ hout_bf,
                                              float* __restrict__ a_src2, float* __restrict__ a_dst2){
    int node = blockIdx.x * 4 + (threadIdx.x >> 6);
    if (node >= NN) return;
    int lane = threadIdx.x & 63;
    int head = lane >> 3;
    float ad = a_dst[(size_t)node * 8 + head];
    const ushort4* h4 = (const ushort4*)hsrc;
    float4 acc = make_float4(0.f, 0.f, 0.f, 0.f);
    float den = 0.f;
    int b = row_ptr[node], en = row_ptr[node + 1];
    int i = b;
    for (; i + 4 <= en; i += 4){
        int s0 = col[i], s1 = col[i+1], s2 = col[i+2], s3 = col[i+3];
        float e0 = a_src[(size_t)s0 * 8 + head];
        float e1 = a_src[(size_t)s1 * 8 + head];
        float e2 = a_src[(size_t)s2 * 8 + head];
        float e3 = a_src[(size_t)s3 * 8 + head];
        ushort4 v0 = h4[(size_t)s0 * 64 + lane];
        ushort4 v1 = h4[(size_t)s1 * 64 + lane];
        ushort4 v2 = h4[(size_t)s2 * 64 + lane];
        ushort4 v3 = h4[(size_t)s3 * 64 + lane];
        float p0 = __expf(lrelu(e0 + ad));
        float p1 = __expf(lrelu(e1 + ad));
        float p2 = __expf(lrelu(e2 + ad));
        float p3 = __expf(lrelu(e3 + ad));
        acc.x += p0*bf2f(v0.x) + p1*bf2f(v1.x) + p2*bf2f(v2.x) + p3*bf2f(v3.x);
        acc.y += p0*bf2f(v0.y) + p1*bf2f(v1.y) + p2*bf2f(v2.y) + p3*bf2f(v3.y);
        acc.z += p0*bf2f(v0.z) + p1*bf2f(v1.z) + p2*bf2f(v2.z) + p3*bf2f(v3.z);
        acc.w += p0*bf2f(v0.w) + p1*bf2f(v1.w) + p2*bf2f(v2.w) + p3*bf2f(v3.w);
        den += p0 + p1 + p2 + p3;
    }
    for (; i < en; ++i){
        int s = col[i];
        float p = __expf(lrelu(a_src[(size_t)s * 8 + head] + ad));
        ushort4 v = h4[(size_t)s * 64 + lane];
        acc.x += p * bf2f(v.x); acc.y += p * bf2f(v.y);
        acc.z += p * bf2f(v.z); acc.w += p * bf2f(v.w);
        den += p;
    }
    float inv = 1.f / (den + 1e-16f);
    float4 bb = ((const float4*)b1)[lane];
    float4 o;
    o.x = fmaxf(acc.x * inv + bb.x, 0.f);
    o.y = fmaxf(acc.y * inv + bb.y, 0.f);
    o.z = fmaxf(acc.z * inv + bb.z, 0.f);
    o.w = fmaxf(acc.w * inv + bb.w, 0.f);
    ushort4 ob; ob.x = f2bf(o.x); ob.y = f2bf(o.y); ob.z = f2bf(o.z); ob.w = f2bf(o.w);
    ((ushort4*)hout_bf)[(size_t)node * 64 + lane] = ob;
    // fused layer-2 attention scores: ss = <h_row, wt2_src>, sd = <h_row, wt2_dst>
    float4 ws4 = ((const float4*)wt2)[lane];          // src half
    float4 wd4 = ((const float4*)(wt2 + 256))[lane];  // dst half
    float ss = o.x*ws4.x + o.y*ws4.y + o.z*ws4.z + o.w*ws4.w;
    float sd = o.x*wd4.x + o.y*wd4.y + o.z*wd4.z + o.w*wd4.w;
    #pragma unroll
    for (int off = 32; off > 0; off >>= 1){
        ss += __shfl_xor(ss, off);
        sd += __shfl_xor(sd, off);
    }
    if (lane == 0){ a_src2[node] = ss; a_dst2[node] = sd; }
}

// ---------------- layer-2 aggregation: wave/node, bf16 gathers, batch-4, +bias ----------
__global__ __launch_bounds__(256) void k_agg2(const ushort* __restrict__ h2bf, const float* __restrict__ a_src2,
                                              const float* __restrict__ a_dst2, const int* __restrict__ row_ptr,
                                              const int* __restrict__ col, const float* __restrict__ b2,
                                              float* __restrict__ out){
    int node = blockIdx.x * 4 + (threadIdx.x >> 6);
    if (node >= NN) return;
    int lane = threadIdx.x & 63;
    float ad = a_dst2[node];
    float acc = 0.f, den = 0.f;
    int b = row_ptr[node], en = row_ptr[node + 1];
    int i = b;
    for (; i + 4 <= en; i += 4){
        int s0 = col[i], s1 = col[i+1], s2 = col[i+2], s3 = col[i+3];
        float e0 = a_src2[s0], e1 = a_src2[s1], e2 = a_src2[s2], e3 = a_src2[s3];
        ushort u0 = h2bf[(size_t)s0 * 64 + lane];
        ushort u1 = h2bf[(size_t)s1 * 64 + lane];
        ushort u2 = h2bf[(size_t)s2 * 64 + lane];
        ushort u3 = h2bf[(size_t)s3 * 64 + lane];
        float p0 = __expf(lrelu(e0 + ad));
        float p1 = __expf(lrelu(e1 + ad));
        float p2 = __expf(lrelu(e2 + ad));
        float p3 = __expf(lrelu(e3 + ad));
        acc += p0*bf2f(u0) + p1*bf2f(u1) + p2*bf2f(u2) + p3*bf2f(u3);
        den += p0 + p1 + p2 + p3;
    }
    for (; i < en; ++i){
        int s = col[i];
        float p = __expf(lrelu(a_src2[s] + ad));
        acc += p * bf2f(h2bf[(size_t)s * 64 + lane]);
        den += p;
    }
    out[(size_t)node * 64 + lane] = acc / (den + 1e-16f) + b2[lane];
}

// ---------------- host ----------------
extern "C" void kernel_launch(void* const* d_in, const int* in_sizes, int n_in,
                              void* d_out, int out_size, void* d_ws, size_t ws_size,
                              hipStream_t stream){
    const float* x        = (const float*)d_in[0];
    const int*   ei       = (const int*)  d_in[1];
    const float* Wsrc1    = (const float*)d_in[2];
    const float* Wdst1    = (const float*)d_in[3];
    const float* att_src1 = (const float*)d_in[4];
    const float* att_dst1 = (const float*)d_in[5];
    const float* b1       = (const float*)d_in[6];
    const float* Wsrc2    = (const float*)d_in[7];
    const float* Wdst2    = (const float*)d_in[8];
    const float* att_src2 = (const float*)d_in[9];
    const float* att_dst2 = (const float*)d_in[10];
    const float* b2       = (const float*)d_in[11];
    float* out = (float*)d_out;
    const int* srcp = ei;
    const int* dstp = ei + EE;

    char* base = (char*)d_ws;
    ushort* hbf1   = (ushort*)base;  base += (size_t)NN * 256 * 2;   // h_src1 bf16
    ushort* hrel   = (ushort*)base;  base += (size_t)NN * 256 * 2;   // relu(layer1) bf16
    ushort* h2bf   = (ushort*)base;  base += (size_t)NN * 64 * 2;    // h_src2 bf16
    float*  a_src1 = (float*)base;   base += (size_t)NN * 8 * 4;
    float*  a_dst1 = (float*)base;   base += (size_t)NN * 8 * 4;
    float*  a_src2 = (float*)base;   base += (size_t)NN * 4;
    float*  a_dst2 = (float*)base;   base += (size_t)NN * 4;
    ushort* wt1bf  = (ushort*)base;  base += 2048 * 2;
    float*  wt2    = (float*)base;   base += 512 * 4;
    ushort* w1t    = (ushort*)base;  base += 32768 * 2;
    ushort* w2t    = (ushort*)base;  base += 16384 * 2;
    int* deg     = (int*)base;       base += (size_t)NN * 4;
    int* row_ptr = (int*)base;       base += (size_t)(NN + 1) * 4;
    int* rank    = (int*)base;       base += (size_t)EE * 4;
    int* col     = (int*)base;       base += (size_t)EE * 4;

    hipMemsetAsync(deg, 0, NN * sizeof(int), stream);

    k_build_wt1<<<8, 256, 0, stream>>>(Wsrc1, Wdst1, att_src1, att_dst1, wt1bf);
    k_build_wt2<<<2, 256, 0, stream>>>(Wsrc2, Wdst2, att_src2, att_dst2, wt2);
    k_prep_w1t<<<128, 256, 0, stream>>>(Wsrc1, w1t);
    k_prep_w2t<<<64, 256, 0, stream>>>(Wsrc2, w2t);

    k_hist<<<(EE + 255) / 256, 256, 0, stream>>>(dstp, deg, rank);
    k_scan<<<1, 1024, 0, stream>>>(deg, row_ptr);
    k_scatter<<<(EE + 255) / 256, 256, 0, stream>>>(srcp, dstp, row_ptr, rank, col);

    dim3 g1((NN + 63) / 64, 2);
    k_gemm1_mfma<<<g1, 256, 0, stream>>>(x, w1t, wt1bf, hbf1, a_src1, a_dst1);

    k_agg1<<<(NN + 3) / 4, 256, 0, stream>>>(hbf1, a_src1, a_dst1, row_ptr, col, b1, wt2,
                                             hrel, a_src2, a_dst2);

    k_gemm2_mfma<<<(NN + 63) / 64, 256, 0, stream>>>(hrel, w2t, h2bf);

    k_agg2<<<(NN + 3) / 4, 256, 0, stream>>>(h2bf, a_src2, a_dst2, row_ptr, col, b2, out);
}

// Round 5
// 215.278 us; speedup vs baseline: 2.2863x; 1.3118x over previous
//
#include <hip/hip_runtime.h>
#include <hip/hip_bf16.h>
#include <cstdint>
#include <cstddef>

#define NN    50000
#define FIN   128
#define EE    800000
#define HID_  32
#define HEADS_ 8
#define EMB_  64
#define NEG   0.2f
#define NB_SCAN 196   // ceil(NN/256)

typedef short bf16x8 __attribute__((ext_vector_type(8)));
typedef float f32x4  __attribute__((ext_vector_type(4)));

static __device__ __forceinline__ float lrelu(float v){ return v < 0.f ? NEG * v : v; }
static __device__ __forceinline__ ushort f2bf(float f){
    uint u = __float_as_uint(f);
    uint r = (u + 0x7FFFu + ((u >> 16) & 1u)) >> 16;   // RNE
    return (ushort)r;
}
static __device__ __forceinline__ float bf2f(ushort u){
    return __uint_as_float(((uint)u) << 16);
}

// ---------------- fold att vectors into small projection matrices ----------------
// wt1bf[j][f] (16 x 128 bf16): j<8 -> src head j ; j>=8 -> dst head j-8
__global__ void k_build_wt1(const float* __restrict__ Wsrc, const float* __restrict__ Wdst,
                            const float* __restrict__ asrc, const float* __restrict__ adst,
                            ushort* __restrict__ wt1bf){
    int idx = blockIdx.x * blockDim.x + threadIdx.x;
    if (idx >= FIN * 16) return;
    int f = idx >> 4, j = idx & 15;
    const float* W; const float* a; int h;
    if (j < 8) { W = Wsrc; a = asrc; h = j; } else { W = Wdst; a = adst; h = j - 8; }
    float s = 0.f;
    #pragma unroll
    for (int c = 0; c < HID_; ++c)
        s += W[(size_t)f * (HEADS_ * HID_) + h * HID_ + c] * a[h * HID_ + c];
    wt1bf[j * 128 + f] = f2bf(s);
}

// wt2[j*256+f], j=0 src, j=1 dst (f32)
__global__ void k_build_wt2(const float* __restrict__ Wsrc, const float* __restrict__ Wdst,
                            const float* __restrict__ asrc, const float* __restrict__ adst,
                            float* __restrict__ wt2){
    int idx = blockIdx.x * blockDim.x + threadIdx.x;
    if (idx >= 256 * 2) return;
    int f = idx >> 1, j = idx & 1;
    const float* W = j ? Wdst : Wsrc;
    const float* a = j ? adst : asrc;
    float s = 0.f;
    #pragma unroll
    for (int c = 0; c < EMB_; ++c) s += W[(size_t)f * EMB_ + c] * a[c];
    wt2[j * 256 + f] = s;
}

// W1 (f32 [128][256]) -> W1T (bf16 [256][128])
__global__ void k_prep_w1t(const float* __restrict__ W, ushort* __restrict__ w1t){
    int idx = blockIdx.x * blockDim.x + threadIdx.x;   // 32768
    if (idx >= 256 * 128) return;
    int n = idx >> 7, k = idx & 127;
    w1t[idx] = f2bf(W[(size_t)k * 256 + n]);
}

// W2 (f32 [256][64]) -> W2T (bf16 [64][256])
__global__ void k_prep_w2t(const float* __restrict__ W, ushort* __restrict__ w2t){
    int idx = blockIdx.x * blockDim.x + threadIdx.x;   // 16384
    if (idx >= 64 * 256) return;
    int n = idx >> 8, k = idx & 255;
    w2t[idx] = f2bf(W[(size_t)k * 64 + n]);
}

// ---------------- CSR build ----------------
__global__ void k_hist(const int* __restrict__ dst, int* __restrict__ deg, int* __restrict__ rank){
    int e = blockIdx.x * blockDim.x + threadIdx.x;
    if (e < EE) rank[e] = atomicAdd(&deg[dst[e]], 1);
}

// phase 1: per-block (256-wide) exclusive prefix + block totals
__global__ __launch_bounds__(256) void k_scan1(const int* __restrict__ deg,
                                               int* __restrict__ pre, int* __restrict__ bsum){
    __shared__ int s[256];
    int tid = threadIdx.x;
    int i = blockIdx.x * 256 + tid;
    int v = (i < NN) ? deg[i] : 0;
    s[tid] = v;
    __syncthreads();
    #pragma unroll
    for (int off = 1; off < 256; off <<= 1){
        int t = (tid >= off) ? s[tid - off] : 0;
        __syncthreads();
        s[tid] += t;
        __syncthreads();
    }
    if (i < NN) pre[i] = s[tid] - v;          // exclusive within block
    if (tid == 255) bsum[blockIdx.x] = s[255];
}

// phase 2: exclusive scan of 196 block sums (single block)
__global__ __launch_bounds__(256) void k_scan2(const int* __restrict__ bsum,
                                               int* __restrict__ boff, int* __restrict__ row_ptr){
    __shared__ int s[256];
    int tid = threadIdx.x;
    int v = (tid < NB_SCAN) ? bsum[tid] : 0;
    s[tid] = v;
    __syncthreads();
    #pragma unroll
    for (int off = 1; off < 256; off <<= 1){
        int t = (tid >= off) ? s[tid - off] : 0;
        __syncthreads();
        s[tid] += t;
        __syncthreads();
    }
    if (tid < NB_SCAN) boff[tid] = s[tid] - v;
    if (tid == 255) row_ptr[NN] = s[255];
}

// phase 3: row_ptr[i] = pre[i] + boff[blk]
__global__ __launch_bounds__(256) void k_scan3(const int* __restrict__ pre, const int* __restrict__ boff,
                                               int* __restrict__ row_ptr){
    int i = blockIdx.x * 256 + threadIdx.x;
    if (i < NN) row_ptr[i] = pre[i] + boff[blockIdx.x];
}

__global__ void k_scatter(const int* __restrict__ src, const int* __restrict__ dst,
                          const int* __restrict__ row_ptr, const int* __restrict__ rank,
                          int* __restrict__ col){
    int e = blockIdx.x * blockDim.x + threadIdx.x;
    if (e < EE){
        int d = dst[e];
        col[row_ptr[d] + rank[e]] = src[e];
    }
}

// ---------------- MFMA bf16 GEMM layer 1 + fused attention scores ----------------
// hbuf_bf[N,256] = bf16( x[N,128] @ W1[128,256] ); blockIdx.y==0 also emits
// a_src1/a_dst1[N,8] = x @ wt1 via one extra B-fragment.
__global__ __launch_bounds__(256) void k_gemm1_mfma(const float* __restrict__ x,
                                                    const ushort* __restrict__ w1t,   // [256][128] bf16
                                                    const ushort* __restrict__ wt1bf, // [16][128] bf16
                                                    ushort* __restrict__ c,           // [NN][256] bf16
                                                    float* __restrict__ a_src1,
                                                    float* __restrict__ a_dst1){
    __shared__ ushort As[64][136];
    __shared__ ushort Bs[128][136];
    __shared__ ushort Bsa[16][136];
    const int tid = threadIdx.x;
    const int m0 = blockIdx.x * 64;
    const int n0 = blockIdx.y * 128;
    // stage A: 64 rows x 128 f32 -> bf16
    #pragma unroll
    for (int i = 0; i < 8; ++i){
        int idx = tid + i * 256;
        int r = idx >> 5, c4 = idx & 31;
        int m = m0 + r;
        float4 v = make_float4(0.f, 0.f, 0.f, 0.f);
        if (m < NN) v = *(const float4*)&x[(size_t)m * FIN + c4 * 4];
        ushort4 u; u.x = f2bf(v.x); u.y = f2bf(v.y); u.z = f2bf(v.z); u.w = f2bf(v.w);
        *(ushort4*)&As[r][c4 * 4] = u;
    }
    // stage B: 128 n-rows x 128 k bf16
    #pragma unroll
    for (int i = 0; i < 8; ++i){
        int idx = tid + i * 256;
        int r = idx >> 4, c8 = idx & 15;
        const ushort4* s4 = (const ushort4*)&w1t[(size_t)(n0 + r) * 128 + c8 * 8];
        *(ushort4*)&Bs[r][c8 * 8]     = s4[0];
        *(ushort4*)&Bs[r][c8 * 8 + 4] = s4[1];
    }
    // stage Bsa: 16 x 128 bf16 (only needed when y==0) — both halves
    if (blockIdx.y == 0){
        int r = tid >> 4, c8 = tid & 15;
        const ushort4* s4 = (const ushort4*)&wt1bf[r * 128 + c8 * 8];
        *(ushort4*)&Bsa[r][c8 * 8]     = s4[0];
        *(ushort4*)&Bsa[r][c8 * 8 + 4] = s4[1];
    }
    __syncthreads();
    const int lane = tid & 63;
    const int w    = tid >> 6;
    const int mr   = lane & 15;
    const int kg   = lane >> 4;
    f32x4 acc[8];
    #pragma unroll
    for (int i = 0; i < 8; ++i) acc[i] = (f32x4){0.f, 0.f, 0.f, 0.f};
    f32x4 acca = (f32x4){0.f, 0.f, 0.f, 0.f};
    #pragma unroll
    for (int ks = 0; ks < 4; ++ks){
        bf16x8 a = *(const bf16x8*)&As[w * 16 + mr][ks * 32 + kg * 8];
        #pragma unroll
        for (int nf = 0; nf < 8; ++nf){
            bf16x8 b = *(const bf16x8*)&Bs[nf * 16 + mr][ks * 32 + kg * 8];
            acc[nf] = __builtin_amdgcn_mfma_f32_16x16x32_bf16(a, b, acc[nf], 0, 0, 0);
        }
        if (blockIdx.y == 0){
            bf16x8 ba = *(const bf16x8*)&Bsa[mr][ks * 32 + kg * 8];
            acca = __builtin_amdgcn_mfma_f32_16x16x32_bf16(a, ba, acca, 0, 0, 0);
        }
    }
    #pragma unroll
    for (int nf = 0; nf < 8; ++nf){
        int colb = n0 + nf * 16 + mr;
        #pragma unroll
        for (int r = 0; r < 4; ++r){
            int row = m0 + w * 16 + kg * 4 + r;
            if (row < NN) c[(size_t)row * 256 + colb] = f2bf(acc[nf][r]);
        }
    }
    if (blockIdx.y == 0){
        int j = mr;
        #pragma unroll
        for (int r = 0; r < 4; ++r){
            int row = m0 + w * 16 + kg * 4 + r;
            if (row < NN){
                if (j < 8) a_src1[(size_t)row * 8 + j]       = acca[r];
                else       a_dst1[(size_t)row * 8 + (j - 8)] = acca[r];
            }
        }
    }
}

// ---------------- MFMA bf16 GEMM layer 2: h2[N,64] = bf16( h[N,256] @ W2[256,64] ) -------
__global__ __launch_bounds__(256) void k_gemm2_mfma(const ushort* __restrict__ hbf,   // [NN][256]
                                                    const ushort* __restrict__ w2t,   // [64][256]
                                                    ushort* __restrict__ c2){         // [NN][64]
    __shared__ ushort As[64][264];
    __shared__ ushort Bs[64][264];
    const int tid = threadIdx.x;
    const int m0 = blockIdx.x * 64;
    #pragma unroll
    for (int i = 0; i < 8; ++i){
        int idx = tid + i * 256;
        int r = idx >> 5, c8 = idx & 31;
        int m = m0 + r;
        ushort4 v0 = make_ushort4(0,0,0,0), v1 = make_ushort4(0,0,0,0);
        if (m < NN){
            const ushort4* s4 = (const ushort4*)&hbf[(size_t)m * 256 + c8 * 8];
            v0 = s4[0]; v1 = s4[1];
        }
        *(ushort4*)&As[r][c8 * 8]     = v0;
        *(ushort4*)&As[r][c8 * 8 + 4] = v1;
    }
    #pragma unroll
    for (int i = 0; i < 8; ++i){
        int idx = tid + i * 256;
        int r = idx >> 5, c8 = idx & 31;
        const ushort4* s4 = (const ushort4*)&w2t[(size_t)r * 256 + c8 * 8];
        *(ushort4*)&Bs[r][c8 * 8]     = s4[0];
        *(ushort4*)&Bs[r][c8 * 8 + 4] = s4[1];
    }
    __syncthreads();
    const int lane = tid & 63;
    const int w    = tid >> 6;
    const int mr   = lane & 15;
    const int kg   = lane >> 4;
    f32x4 acc[4];
    #pragma unroll
    for (int i = 0; i < 4; ++i) acc[i] = (f32x4){0.f, 0.f, 0.f, 0.f};
    #pragma unroll
    for (int ks = 0; ks < 8; ++ks){
        bf16x8 a = *(const bf16x8*)&As[w * 16 + mr][ks * 32 + kg * 8];
        #pragma unroll
        for (int nf = 0; nf < 4; ++nf){
            bf16x8 b = *(const bf16x8*)&Bs[nf * 16 + mr][ks * 32 + kg * 8];
            acc[nf] = __builtin_amdgcn_mfma_f32_16x16x32_bf16(a, b, acc[nf], 0, 0, 0);
        }
    }
    #pragma unroll
    for (int nf = 0; nf < 4; ++nf){
        int colb = nf * 16 + mr;
        #pragma unroll
        for (int r = 0; r < 4; ++r){
            int row = m0 + w * 16 + kg * 4 + r;
            if (row < NN) c2[(size_t)row * 64 + colb] = f2bf(acc[nf][r]);
        }
    }
}

// ---------------- layer-1 aggregation (wave/node, batch-4 gathers) + fused layer-2 scores -
__global__ __launch_bounds__(256) void k_agg1(const ushort* __restrict__ hsrc, const float* __restrict__ a_src,
                                              const float* __restrict__ a_dst, const int* __restrict__ row_ptr,
                                              const int* __restrict__ col, const float* __restrict__ b1,
                                              const float* __restrict__ wt2,
                                              ushort* __restrict__ hout_bf,
                                              float* __restrict__ a_src2, float* __restrict__ a_dst2){
    int node = blockIdx.x * 4 + (threadIdx.x >> 6);
    if (node >= NN) return;
    int lane = threadIdx.x & 63;
    int head = lane >> 3;
    float ad = a_dst[(size_t)node * 8 + head];
    const ushort4* h4 = (const ushort4*)hsrc;
    float4 acc = make_float4(0.f, 0.f, 0.f, 0.f);
    float den = 0.f;
    int b = row_ptr[node], en = row_ptr[node + 1];
    int i = b;
    for (; i + 4 <= en; i += 4){
        int s0 = col[i], s1 = col[i+1], s2 = col[i+2], s3 = col[i+3];
        float e0 = a_src[(size_t)s0 * 8 + head];
        float e1 = a_src[(size_t)s1 * 8 + head];
        float e2 = a_src[(size_t)s2 * 8 + head];
        float e3 = a_src[(size_t)s3 * 8 + head];
        ushort4 v0 = h4[(size_t)s0 * 64 + lane];
        ushort4 v1 = h4[(size_t)s1 * 64 + lane];
        ushort4 v2 = h4[(size_t)s2 * 64 + lane];
        ushort4 v3 = h4[(size_t)s3 * 64 + lane];
        float p0 = __expf(lrelu(e0 + ad));
        float p1 = __expf(lrelu(e1 + ad));
        float p2 = __expf(lrelu(e2 + ad));
        float p3 = __expf(lrelu(e3 + ad));
        acc.x += p0*bf2f(v0.x) + p1*bf2f(v1.x) + p2*bf2f(v2.x) + p3*bf2f(v3.x);
        acc.y += p0*bf2f(v0.y) + p1*bf2f(v1.y) + p2*bf2f(v2.y) + p3*bf2f(v3.y);
        acc.z += p0*bf2f(v0.z) + p1*bf2f(v1.z) + p2*bf2f(v2.z) + p3*bf2f(v3.z);
        acc.w += p0*bf2f(v0.w) + p1*bf2f(v1.w) + p2*bf2f(v2.w) + p3*bf2f(v3.w);
        den += p0 + p1 + p2 + p3;
    }
    for (; i < en; ++i){
        int s = col[i];
        float p = __expf(lrelu(a_src[(size_t)s * 8 + head] + ad));
        ushort4 v = h4[(size_t)s * 64 + lane];
        acc.x += p * bf2f(v.x); acc.y += p * bf2f(v.y);
        acc.z += p * bf2f(v.z); acc.w += p * bf2f(v.w);
        den += p;
    }
    float inv = 1.f / (den + 1e-16f);
    float4 bb = ((const float4*)b1)[lane];
    float4 o;
    o.x = fmaxf(acc.x * inv + bb.x, 0.f);
    o.y = fmaxf(acc.y * inv + bb.y, 0.f);
    o.z = fmaxf(acc.z * inv + bb.z, 0.f);
    o.w = fmaxf(acc.w * inv + bb.w, 0.f);
    ushort4 ob; ob.x = f2bf(o.x); ob.y = f2bf(o.y); ob.z = f2bf(o.z); ob.w = f2bf(o.w);
    ((ushort4*)hout_bf)[(size_t)node * 64 + lane] = ob;
    // fused layer-2 attention scores: ss = <h_row, wt2_src>, sd = <h_row, wt2_dst>
    float4 ws4 = ((const float4*)wt2)[lane];          // src half
    float4 wd4 = ((const float4*)(wt2 + 256))[lane];  // dst half
    float ss = o.x*ws4.x + o.y*ws4.y + o.z*ws4.z + o.w*ws4.w;
    float sd = o.x*wd4.x + o.y*wd4.y + o.z*wd4.z + o.w*wd4.w;
    #pragma unroll
    for (int off = 32; off > 0; off >>= 1){
        ss += __shfl_xor(ss, off);
        sd += __shfl_xor(sd, off);
    }
    if (lane == 0){ a_src2[node] = ss; a_dst2[node] = sd; }
}

// ---------------- layer-2 aggregation: wave/node, bf16 gathers, batch-4, +bias ----------
__global__ __launch_bounds__(256) void k_agg2(const ushort* __restrict__ h2bf, const float* __restrict__ a_src2,
                                              const float* __restrict__ a_dst2, const int* __restrict__ row_ptr,
                                              const int* __restrict__ col, const float* __restrict__ b2,
                                              float* __restrict__ out){
    int node = blockIdx.x * 4 + (threadIdx.x >> 6);
    if (node >= NN) return;
    int lane = threadIdx.x & 63;
    float ad = a_dst2[node];
    float acc = 0.f, den = 0.f;
    int b = row_ptr[node], en = row_ptr[node + 1];
    int i = b;
    for (; i + 4 <= en; i += 4){
        int s0 = col[i], s1 = col[i+1], s2 = col[i+2], s3 = col[i+3];
        float e0 = a_src2[s0], e1 = a_src2[s1], e2 = a_src2[s2], e3 = a_src2[s3];
        ushort u0 = h2bf[(size_t)s0 * 64 + lane];
        ushort u1 = h2bf[(size_t)s1 * 64 + lane];
        ushort u2 = h2bf[(size_t)s2 * 64 + lane];
        ushort u3 = h2bf[(size_t)s3 * 64 + lane];
        float p0 = __expf(lrelu(e0 + ad));
        float p1 = __expf(lrelu(e1 + ad));
        float p2 = __expf(lrelu(e2 + ad));
        float p3 = __expf(lrelu(e3 + ad));
        acc += p0*bf2f(u0) + p1*bf2f(u1) + p2*bf2f(u2) + p3*bf2f(u3);
        den += p0 + p1 + p2 + p3;
    }
    for (; i < en; ++i){
        int s = col[i];
        float p = __expf(lrelu(a_src2[s] + ad));
        acc += p * bf2f(h2bf[(size_t)s * 64 + lane]);
        den += p;
    }
    out[(size_t)node * 64 + lane] = acc / (den + 1e-16f) + b2[lane];
}

// ---------------- host ----------------
extern "C" void kernel_launch(void* const* d_in, const int* in_sizes, int n_in,
                              void* d_out, int out_size, void* d_ws, size_t ws_size,
                              hipStream_t stream){
    const float* x        = (const float*)d_in[0];
    const int*   ei       = (const int*)  d_in[1];
    const float* Wsrc1    = (const float*)d_in[2];
    const float* Wdst1    = (const float*)d_in[3];
    const float* att_src1 = (const float*)d_in[4];
    const float* att_dst1 = (const float*)d_in[5];
    const float* b1       = (const float*)d_in[6];
    const float* Wsrc2    = (const float*)d_in[7];
    const float* Wdst2    = (const float*)d_in[8];
    const float* att_src2 = (const float*)d_in[9];
    const float* att_dst2 = (const float*)d_in[10];
    const float* b2       = (const float*)d_in[11];
    float* out = (float*)d_out;
    const int* srcp = ei;
    const int* dstp = ei + EE;

    char* base = (char*)d_ws;
    ushort* hbf1   = (ushort*)base;  base += (size_t)NN * 256 * 2;   // h_src1 bf16
    ushort* hrel   = (ushort*)base;  base += (size_t)NN * 256 * 2;   // relu(layer1) bf16
    ushort* h2bf   = (ushort*)base;  base += (size_t)NN * 64 * 2;    // h_src2 bf16
    float*  a_src1 = (float*)base;   base += (size_t)NN * 8 * 4;
    float*  a_dst1 = (float*)base;   base += (size_t)NN * 8 * 4;
    float*  a_src2 = (float*)base;   base += (size_t)NN * 4;
    float*  a_dst2 = (float*)base;   base += (size_t)NN * 4;
    ushort* wt1bf  = (ushort*)base;  base += 2048 * 2;
    float*  wt2    = (float*)base;   base += 512 * 4;
    ushort* w1t    = (ushort*)base;  base += 32768 * 2;
    ushort* w2t    = (ushort*)base;  base += 16384 * 2;
    int* deg     = (int*)base;       base += (size_t)NN * 4;
    int* row_ptr = (int*)base;       base += (size_t)(NN + 1) * 4;
    int* rank    = (int*)base;       base += (size_t)EE * 4;
    int* col     = (int*)base;       base += (size_t)EE * 4;
    int* pre     = (int*)base;       base += (size_t)NN * 4;
    int* bsum    = (int*)base;       base += 256 * 4;
    int* boff    = (int*)base;       base += 256 * 4;

    hipMemsetAsync(deg, 0, NN * sizeof(int), stream);

    k_build_wt1<<<8, 256, 0, stream>>>(Wsrc1, Wdst1, att_src1, att_dst1, wt1bf);
    k_build_wt2<<<2, 256, 0, stream>>>(Wsrc2, Wdst2, att_src2, att_dst2, wt2);
    k_prep_w1t<<<128, 256, 0, stream>>>(Wsrc1, w1t);
    k_prep_w2t<<<64, 256, 0, stream>>>(Wsrc2, w2t);

    k_hist<<<(EE + 255) / 256, 256, 0, stream>>>(dstp, deg, rank);
    k_scan1<<<NB_SCAN, 256, 0, stream>>>(deg, pre, bsum);
    k_scan2<<<1, 256, 0, stream>>>(bsum, boff, row_ptr);
    k_scan3<<<NB_SCAN, 256, 0, stream>>>(pre, boff, row_ptr);
    k_scatter<<<(EE + 255) / 256, 256, 0, stream>>>(srcp, dstp, row_ptr, rank, col);

    dim3 g1((NN + 63) / 64, 2);
    k_gemm1_mfma<<<g1, 256, 0, stream>>>(x, w1t, wt1bf, hbf1, a_src1, a_dst1);

    k_agg1<<<(NN + 3) / 4, 256, 0, stream>>>(hbf1, a_src1, a_dst1, row_ptr, col, b1, wt2,
                                             hrel, a_src2, a_dst2);

    k_gemm2_mfma<<<(NN + 63) / 64, 256, 0, stream>>>(hrel, w2t, h2bf);

    k_agg2<<<(NN + 3) / 4, 256, 0, stream>>>(h2bf, a_src2, a_dst2, row_ptr, col, b2, out);
}